// Round 13
// baseline (430.268 us; speedup 1.0000x reference)
//
#include <hip/hip_runtime.h>
#include <hip/hip_bf16.h>

#define ND 128   // node feature dim (= H*C)
#define NH 8
#define NC 16

typedef float v2f __attribute__((ext_vector_type(2)));
typedef short bf16x8 __attribute__((ext_vector_type(8)));
typedef float f32x4 __attribute__((ext_vector_type(4)));

static inline size_t alignup(size_t x){ return (x + 255) & ~size_t(255); }

__device__ __forceinline__ ushort f2bf(float f){
    __hip_bfloat16 h = __float2bfloat16(f);
    return *reinterpret_cast<ushort*>(&h);
}

// unpack 2 packed bf16 (lo=ch0, hi=ch1) to packed f32 pair
__device__ __forceinline__ v2f unpack_bf2(uint u){
    v2f r;
    r.x = __uint_as_float(u << 16);
    r.y = __uint_as_float(u & 0xffff0000u);
    return r;
}

__device__ __forceinline__ v2f lrelu2(v2f z){
    v2f s = z * 0.2f;
    v2f r;
    r.x = fmaxf(z.x, s.x);
    r.y = fmaxf(z.y, s.y);
    return r;
}

// sum over each aligned 8-lane group (head group), pure-VALU DPP butterfly
__device__ __forceinline__ float hred8(float x){
    int y;
    y = __builtin_amdgcn_mov_dpp(__float_as_int(x), 0xB1, 0xF, 0xF, true);
    x += __int_as_float(y);
    y = __builtin_amdgcn_mov_dpp(__float_as_int(x), 0x4E, 0xF, 0xF, true);
    x += __int_as_float(y);
    y = __builtin_amdgcn_mov_dpp(__float_as_int(x), 0x141, 0xF, 0xF, true);
    x += __int_as_float(y);
    return x;
}

// ---------------- fused prep: weight transpose/convert + degree histogram ----------------

struct WSrc { const float* p[6]; };

#define WTHREADS (6 * 16384)

__global__ void prep_kernel(WSrc s, ushort* __restrict__ wt,
                            const int* __restrict__ dsts, int* __restrict__ deg, int E)
{
    int id = blockIdx.x * blockDim.x + threadIdx.x;
    if (id < WTHREADS) {
        int m = id >> 14;
        int r = id & 16383;
        int n = r >> 7, k = r & 127;
        wt[(size_t)m * 16384 + n * 128 + k] = f2bf(s.p[m][k * 128 + n]);
    } else {
        int e4 = (id - WTHREADS) * 4;
        if (e4 + 3 < E) {
            int4 d = *(const int4*)(dsts + e4);
            atomicAdd(&deg[d.x], 1);
            atomicAdd(&deg[d.y], 1);
            atomicAdd(&deg[d.z], 1);
            atomicAdd(&deg[d.w], 1);
        } else if (e4 < E) {
            for (int e = e4; e < E; ++e) atomicAdd(&deg[dsts[e]], 1);
        }
    }
}

// rowstart = exclusive cumsum of PADDED degrees (each row padded to multiple of 4), int4-vectorized
__global__ __launch_bounds__(1024) void scan_kernel(const int* __restrict__ deg,
                                                    int* __restrict__ rowstart, int n)
{
    __shared__ int wsum[16];
    int tid = threadIdx.x;
    int lane = tid & 63, wid = tid >> 6;
    int carry = 0;
    for (int base = 0; base < n; base += 4096) {
        int idx = base + tid * 4;
        int4 d = make_int4(0, 0, 0, 0);
        if (idx + 3 < n) d = *(const int4*)(deg + idx);
        else {
            if (idx < n)     d.x = deg[idx];
            if (idx + 1 < n) d.y = deg[idx + 1];
            if (idx + 2 < n) d.z = deg[idx + 2];
        }
        int p0 = (d.x + 3) & ~3, p1 = (d.y + 3) & ~3;
        int p2 = (d.z + 3) & ~3, p3 = (d.w + 3) & ~3;
        int tsum = p0 + p1 + p2 + p3;
        int s = tsum;
        #pragma unroll
        for (int o = 1; o < 64; o <<= 1) {
            int t = __shfl_up(s, o);
            if (lane >= o) s += t;
        }
        if (lane == 63) wsum[wid] = s;
        __syncthreads();
        int off = carry;
        #pragma unroll
        for (int w = 0; w < 16; ++w) {
            int ws_ = wsum[w];
            if (w < wid) off += ws_;
        }
        int total = 0;
        #pragma unroll
        for (int w = 0; w < 16; ++w) total += wsum[w];
        int excl = off + (s - tsum);
        if (idx < n)     rowstart[idx]     = excl;
        if (idx + 1 < n) rowstart[idx + 1] = excl + p0;
        if (idx + 2 < n) rowstart[idx + 2] = excl + p0 + p1;
        if (idx + 3 < n) rowstart[idx + 3] = excl + p0 + p1 + p2;
        carry += total;
        __syncthreads();
    }
    if (tid == 0) rowstart[n] = carry;
}

// fused scatter (ONE random 16B record write per edge) + padfill (pad slots + guard)
// record: {src*256, ea_bf16(ch0,ch1), ea_bf16(ch2,ch3), 0}
__global__ void scatter_kernel(const int* __restrict__ srcs, const int* __restrict__ dsts,
                               const float4* __restrict__ ea4,
                               const int* __restrict__ rowstart, const int* __restrict__ deg,
                               int* __restrict__ cursor, uint4* __restrict__ recs, int E, int n)
{
    int id = blockIdx.x * blockDim.x + threadIdx.x;
    if (id < E) {
        int d = dsts[id];
        int pos = rowstart[d] + atomicAdd(&cursor[d], 1);
        float4 a = ea4[id];
        recs[pos] = make_uint4((uint)(srcs[id] << 8),
                               (uint)f2bf(a.x) | ((uint)f2bf(a.y) << 16),
                               (uint)f2bf(a.z) | ((uint)f2bf(a.w) << 16), 0u);
    } else if (id < E + n) {
        int v = id - E;
        int d = deg[v];
        int p = rowstart[v] + d;
        int pe = rowstart[v] + ((d + 3) & ~3);
        for (; p < pe; ++p) recs[p] = make_uint4(0u, 0u, 0u, 0u);
    } else if (id < E + n + 96) {
        int p = rowstart[n] + (id - E - n);
        recs[p] = make_uint4(0u, 0u, 0u, 0u);
    }
}

// ---------------- MFMA GEMM: XL,XR (bf16) = X@{Wl,Wr}+{bl,br} ----------------
// A = X tile split hi/lo bf16 (error ~2^-17), B = WT bf16. 16x16x32 MFMA. (r9-validated)

__global__ __launch_bounds__(256) void gemm_mfma(
    const float* __restrict__ X,
    const ushort* __restrict__ WTl, const float* __restrict__ bl,
    const ushort* __restrict__ WTr, const float* __restrict__ br,
    ushort* __restrict__ XLB, ushort* __restrict__ XRB, int nrows)
{
    __shared__ ushort xhi[64][136];
    __shared__ ushort xlo[64][136];
    int tid = threadIdx.x;
    int row0 = blockIdx.x * 64;

    const float4* X4 = (const float4*)X;
    #pragma unroll
    for (int i = tid; i < 64*32; i += 256) {
        int r = i >> 5, c = i & 31;
        float4 v = make_float4(0.f, 0.f, 0.f, 0.f);
        if (row0 + r < nrows) v = X4[(size_t)(row0 + r) * 32 + c];
        ushort4 h, l;
        h.x = f2bf(v.x); l.x = f2bf(v.x - __uint_as_float((uint)h.x << 16));
        h.y = f2bf(v.y); l.y = f2bf(v.y - __uint_as_float((uint)h.y << 16));
        h.z = f2bf(v.z); l.z = f2bf(v.z - __uint_as_float((uint)h.z << 16));
        h.w = f2bf(v.w); l.w = f2bf(v.w - __uint_as_float((uint)h.w << 16));
        *(ushort4*)&xhi[r][c * 4] = h;
        *(ushort4*)&xlo[r][c * 4] = l;
    }
    __syncthreads();

    int lane = tid & 63;
    int wid = tid >> 6;
    int c15 = lane & 15;
    int kblk = lane >> 4;
    int rowb = wid * 16;

    f32x4 accl[8], accr[8];
    #pragma unroll
    for (int nt = 0; nt < 8; ++nt) {
        float bvl = bl[nt * 16 + c15];
        float bvr = br[nt * 16 + c15];
        accl[nt] = (f32x4){bvl, bvl, bvl, bvl};
        accr[nt] = (f32x4){bvr, bvr, bvr, bvr};
    }

    const bf16x8* WL8 = (const bf16x8*)WTl;
    const bf16x8* WR8 = (const bf16x8*)WTr;

    #pragma unroll
    for (int kc = 0; kc < 4; ++kc) {
        int k0 = kc * 32 + kblk * 8;
        bf16x8 ahi = *(const bf16x8*)&xhi[rowb + c15][k0];
        bf16x8 alo = *(const bf16x8*)&xlo[rowb + c15][k0];
        int kidx = k0 >> 3;
        #pragma unroll
        for (int nt = 0; nt < 8; ++nt) {
            int bi = (nt * 16 + c15) * 16 + kidx;
            bf16x8 bfl = WL8[bi];
            bf16x8 bfr = WR8[bi];
            accl[nt] = __builtin_amdgcn_mfma_f32_16x16x32_bf16(ahi, bfl, accl[nt], 0, 0, 0);
            accl[nt] = __builtin_amdgcn_mfma_f32_16x16x32_bf16(alo, bfl, accl[nt], 0, 0, 0);
            accr[nt] = __builtin_amdgcn_mfma_f32_16x16x32_bf16(ahi, bfr, accr[nt], 0, 0, 0);
            accr[nt] = __builtin_amdgcn_mfma_f32_16x16x32_bf16(alo, bfr, accr[nt], 0, 0, 0);
        }
    }

    int crow = rowb + (lane >> 4) * 4;
    #pragma unroll
    for (int j = 0; j < 4; ++j) {
        int row = row0 + crow + j;
        if (row < nrows) {
            #pragma unroll
            for (int nt = 0; nt < 8; ++nt) {
                XLB[(size_t)row * 128 + nt * 16 + c15] = f2bf(accl[nt][j]);
                XRB[(size_t)row * 128 + nt * 16 + c15] = f2bf(accr[nt][j]);
            }
        }
    }
}

// ---------------- GATv2 edge accumulation: 1 wave/dst, 2 ch/lane (packed f32) -----------
// Unified 16B records; full records loaded 2 batches deep, src-dwords 2 more batches deep
// (keeps SGPR ~r9 level), gathers 3 batches in flight (r9-depth). Guard rows zero-filled.
// CE=true: accumulate edge-attr sums inline and write easum (layer 0); else load easum.

template<bool CE>
__device__ __forceinline__ void gat_wave(
    int dstv, int t,
    const uint* __restrict__ xl_u, const uint* __restrict__ xr_u,
    const int* __restrict__ rowstart, const int* __restrict__ deg,
    const uint4* __restrict__ recs, float4* __restrict__ easum,
    const float* __restrict__ We, const float* __restrict__ att,
    v2f& r_out, float& l_out)
{
    v2f we0  = ((const v2f*)(We))[t];
    v2f we1  = ((const v2f*)(We + ND))[t];
    v2f we2  = ((const v2f*)(We + 2*ND))[t];
    v2f we3  = ((const v2f*)(We + 3*ND))[t];
    v2f attv = ((const v2f*)att)[t] * 1.44269504f;   // log2(e) folded in
    v2f xrv  = unpack_bf2(xr_u[(((uint)dstv) << 6) + t]);

    int p0 = __builtin_amdgcn_readfirstlane(rowstart[dstv]);
    int dv = __builtin_amdgcn_readfirstlane(deg[dstv]);
    int nb = (dv + 3) >> 2;

    uint xsw = xl_u[(((uint)dstv) << 6) + t];   // self-loop xl

    const uint4* rp = recs + p0;                // wave-uniform -> scalar loads
    const uint* rpw = (const uint*)rp;          // dword view: record j's src at rpw[4*j]
    const char* xlc = (const char*)xl_u;
    uint t4 = (uint)t * 4u;

    v2f a = {0.f, 0.f};
    float lsum = 0.f;
    float ssx = 0.f, ssy = 0.f, ssz = 0.f, ssw = 0.f;  // inline ea sums (CE only)

    // prologue: full records batches 0,1; src-only batches 2,3; gathers for 0,1,2
    uint4 rA0 = rp[0], rA1 = rp[1], rA2 = rp[2], rA3 = rp[3];
    uint4 rB0 = rp[4], rB1 = rp[5], rB2 = rp[6], rB3 = rp[7];
    uint sC0 = rpw[32], sC1 = rpw[36], sC2 = rpw[40], sC3 = rpw[44];
    uint sD0 = rpw[48], sD1 = rpw[52], sD2 = rpw[56], sD3 = rpw[60];
    uint gA0 = *(const uint*)(xlc + (rA0.x + t4));
    uint gA1 = *(const uint*)(xlc + (rA1.x + t4));
    uint gA2 = *(const uint*)(xlc + (rA2.x + t4));
    uint gA3 = *(const uint*)(xlc + (rA3.x + t4));
    uint gB0 = *(const uint*)(xlc + (rB0.x + t4));
    uint gB1 = *(const uint*)(xlc + (rB1.x + t4));
    uint gB2 = *(const uint*)(xlc + (rB2.x + t4));
    uint gB3 = *(const uint*)(xlc + (rB3.x + t4));
    uint gC0 = *(const uint*)(xlc + (sC0 + t4));
    uint gC1 = *(const uint*)(xlc + (sC1 + t4));
    uint gC2 = *(const uint*)(xlc + (sC2 + t4));
    uint gC3 = *(const uint*)(xlc + (sC3 + t4));

    for (int ib = 0; ib < nb; ++ib) {
        // gathers for batch ib+3 (from sD), srcs for batch ib+4, full records for ib+2
        uint gD0 = *(const uint*)(xlc + (sD0 + t4));
        uint gD1 = *(const uint*)(xlc + (sD1 + t4));
        uint gD2 = *(const uint*)(xlc + (sD2 + t4));
        uint gD3 = *(const uint*)(xlc + (sD3 + t4));
        int wbase = (ib + 4) * 16;
        uint sE0 = rpw[wbase], sE1 = rpw[wbase + 4], sE2 = rpw[wbase + 8], sE3 = rpw[wbase + 12];
        int rbase = (ib + 2) * 4;
        uint4 rC0 = rp[rbase], rC1 = rp[rbase + 1], rC2 = rp[rbase + 2], rC3 = rp[rbase + 3];

        // unpack ea from current batch's records (wave-uniform)
        float e0x = __uint_as_float(rA0.y << 16), e0y = __uint_as_float(rA0.y & 0xffff0000u);
        float e0z = __uint_as_float(rA0.z << 16), e0w = __uint_as_float(rA0.z & 0xffff0000u);
        float e1x = __uint_as_float(rA1.y << 16), e1y = __uint_as_float(rA1.y & 0xffff0000u);
        float e1z = __uint_as_float(rA1.z << 16), e1w = __uint_as_float(rA1.z & 0xffff0000u);
        float e2x = __uint_as_float(rA2.y << 16), e2y = __uint_as_float(rA2.y & 0xffff0000u);
        float e2z = __uint_as_float(rA2.z << 16), e2w = __uint_as_float(rA2.z & 0xffff0000u);
        float e3x = __uint_as_float(rA3.y << 16), e3y = __uint_as_float(rA3.y & 0xffff0000u);
        float e3z = __uint_as_float(rA3.z << 16), e3w = __uint_as_float(rA3.z & 0xffff0000u);

        if (CE) {
            ssx += (e0x + e1x) + (e2x + e3x);
            ssy += (e0y + e1y) + (e2y + e3y);
            ssz += (e0z + e1z) + (e2z + e3z);
            ssw += (e0w + e1w) + (e2w + e3w);
        }

        // b = xr + ea @ We  (packed f32)
        v2f b0 = xrv + we0*e0x + we1*e0y + we2*e0z + we3*e0w;
        v2f b1 = xrv + we0*e1x + we1*e1y + we2*e1z + we3*e1w;
        v2f b2 = xrv + we0*e2x + we1*e2y + we2*e2z + we3*e2w;
        v2f b3 = xrv + we0*e3x + we1*e3y + we2*e3z + we3*e3w;

        v2f x0 = unpack_bf2(gA0);
        v2f x1 = unpack_bf2(gA1);
        v2f x2 = unpack_bf2(gA2);
        v2f x3 = unpack_bf2(gA3);

        v2f l0 = lrelu2(x0 + b0);
        v2f l1 = lrelu2(x1 + b1);
        v2f l2 = lrelu2(x2 + b2);
        v2f l3 = lrelu2(x3 + b3);

        v2f q0 = l0 * attv;
        v2f q1 = l1 * attv;
        v2f q2 = l2 * attv;
        v2f q3 = l3 * attv;
        float pt0 = q0.x + q0.y;
        float pt1 = q1.x + q1.y;
        float pt2 = q2.x + q2.y;
        float pt3 = q3.x + q3.y;

        // mask only in the last batch (wave-uniform branch)
        if (ib == nb - 1) {
            int live = dv - ib*4;
            pt1 = (live > 1) ? pt1 : -1e30f;
            pt2 = (live > 2) ? pt2 : -1e30f;
            pt3 = (live > 3) ? pt3 : -1e30f;
        }

        // per-head logit reduce (DPP, 4 independent chains)
        float al0 = hred8(pt0);
        float al1 = hred8(pt1);
        float al2 = hred8(pt2);
        float al3 = hred8(pt3);

        // no-max softmax accumulation in log2 domain
        float pe0 = exp2f(al0);
        float pe1 = exp2f(al1);
        float pe2 = exp2f(al2);
        float pe3 = exp2f(al3);
        lsum += (pe0 + pe1) + (pe2 + pe3);
        a += x0 * pe0;
        a += x1 * pe1;
        a += x2 * pe2;
        a += x3 * pe3;

        gA0 = gB0; gA1 = gB1; gA2 = gB2; gA3 = gB3;
        gB0 = gC0; gB1 = gC1; gB2 = gC2; gB3 = gC3;
        gC0 = gD0; gC1 = gD1; gC2 = gD2; gC3 = gD3;
        rA0 = rB0; rA1 = rB1; rA2 = rB2; rA3 = rB3;
        rB0 = rC0; rB1 = rC1; rB2 = rC2; rB3 = rC3;
        sD0 = sE0; sD1 = sE1; sD2 = sE2; sD3 = sE3;
    }

    // self loop: ea = mean of incoming, src = dst
    float4 em;
    if (CE) {
        float inv = 1.0f / (float)(dv > 0 ? dv : 1);
        em = make_float4(ssx * inv, ssy * inv, ssz * inv, ssw * inv);
        if (t == 0) easum[dstv] = em;
    } else {
        em = easum[dstv];                       // uniform -> scalar load
    }
    v2f xs = unpack_bf2(xsw);
    v2f bs = xrv + we0*em.x + we1*em.y + we2*em.z + we3*em.w;
    v2f ls = lrelu2(xs + bs);
    v2f qs = ls * attv;
    float al = hred8(qs.x + qs.y);
    float pe = exp2f(al);
    l_out = lsum + pe;
    r_out = a + xs * pe;
}

// layers 0,1: concat heads, +bias, ELU, LN(128), residual. 4 dst per 256-thread block.
template<bool CE>
__global__ __launch_bounds__(256) void attn_concat(
    const ushort* __restrict__ xlb, const ushort* __restrict__ xrb,
    const float* __restrict__ xin,
    const int* __restrict__ rowstart, const int* __restrict__ deg,
    const uint4* __restrict__ recs, float4* __restrict__ easum,
    const float* __restrict__ We, const float* __restrict__ att,
    const float* __restrict__ bias, const float* __restrict__ g, const float* __restrict__ be,
    float* __restrict__ out, int n)
{
    int wid = threadIdx.x >> 6;
    int t = threadIdx.x & 63;
    int dstv = blockIdx.x * 4 + wid;
    if (dstv >= n) return;

    v2f av; float l;
    gat_wave<CE>(dstv, t, (const uint*)xlb, (const uint*)xrb, rowstart, deg, recs, easum,
                 We, att, av, l);

    v2f bv = ((const v2f*)bias)[t];
    float linv = 1.0f / l;
    v2f h = av * linv + bv;
    h.x = h.x > 0.f ? h.x : (__expf(h.x) - 1.0f);   // ELU
    h.y = h.y > 0.f ? h.y : (__expf(h.y) - 1.0f);

    float ss = h.x + h.y, qq = h.x*h.x + h.y*h.y;
    #pragma unroll
    for (int o = 1; o < 64; o <<= 1) { ss += __shfl_xor(ss, o); qq += __shfl_xor(qq, o); }
    float mu = ss * (1.0f / ND);
    float var = qq * (1.0f / ND) - mu * mu;
    float rstd = rsqrtf(var + 1e-5f);

    v2f gv  = ((const v2f*)g)[t];
    v2f bev = ((const v2f*)be)[t];
    v2f xiv = ((const v2f*)(xin + (size_t)dstv * ND))[t];
    v2f o2 = (h - mu) * rstd * gv + bev + xiv;
    ((v2f*)(out + (size_t)dstv * ND))[t] = o2;
}

// layer 2: mean over heads, +bias, ELU, LN(16), @Wout[16,128]+bout
__global__ __launch_bounds__(256) void attn_final(
    const ushort* __restrict__ xlb, const ushort* __restrict__ xrb,
    const int* __restrict__ rowstart, const int* __restrict__ deg,
    const uint4* __restrict__ recs, float4* __restrict__ easum,
    const float* __restrict__ We, const float* __restrict__ att,
    const float* __restrict__ b2, const float* __restrict__ g2, const float* __restrict__ be2,
    const float* __restrict__ Wout, const float* __restrict__ bout,
    float* __restrict__ out, int n)
{
    __shared__ float h16s[4][16];
    int wid = threadIdx.x >> 6;
    int t = threadIdx.x & 63;
    int dstv = blockIdx.x * 4 + wid;
    if (dstv >= n) return;

    v2f av; float l;
    gat_wave<false>(dstv, t, (const uint*)xlb, (const uint*)xrb, rowstart, deg, recs, easum,
                    We, att, av, l);
    float linv = 1.0f / l;
    float v0 = av.x * linv, v1 = av.y * linv;

    // mean over 8 heads: sum over lanes differing in bits 3,4,5
    #pragma unroll
    for (int o = 8; o < 64; o <<= 1) { v0 += __shfl_xor(v0, o); v1 += __shfl_xor(v1, o); }
    int cc = t & 7;   // channel pair index: channels 2cc, 2cc+1
    float2 b2v = ((const float2*)b2)[cc];
    v0 = v0 * (1.0f / NH) + b2v.x;
    v1 = v1 * (1.0f / NH) + b2v.y;
    v0 = v0 > 0.f ? v0 : (__expf(v0) - 1.0f);
    v1 = v1 > 0.f ? v1 : (__expf(v1) - 1.0f);

    // LN over 16 (values duplicated across the 8 head-groups)
    float ss = v0 + v1, qq = v0*v0 + v1*v1;
    #pragma unroll
    for (int o = 1; o < 8; o <<= 1) { ss += __shfl_xor(ss, o); qq += __shfl_xor(qq, o); }
    float mu = ss * (1.0f / NC);
    float var = qq * (1.0f / NC) - mu * mu;
    float rstd = rsqrtf(var + 1e-5f);
    float2 g2v = ((const float2*)g2)[cc];
    float2 be2v = ((const float2*)be2)[cc];
    float t0 = (v0 - mu) * rstd * g2v.x + be2v.x;
    float t1 = (v1 - mu) * rstd * g2v.y + be2v.y;

    if (t < 8) { h16s[wid][2*t] = t0; h16s[wid][2*t + 1] = t1; }

    float2 ov = ((const float2*)bout)[t];
    #pragma unroll
    for (int k = 0; k < NC; k++) {
        float hk = h16s[wid][k];
        float2 wv = ((const float2*)Wout)[k * 64 + t];
        ov.x = fmaf(hk, wv.x, ov.x);
        ov.y = fmaf(hk, wv.y, ov.y);
    }
    ((float2*)(out + (size_t)dstv * ND))[t] = ov;
}

// ---------------- launch ----------------

extern "C" void kernel_launch(void* const* d_in, const int* in_sizes, int n_in,
                              void* d_out, int out_size, void* d_ws, size_t ws_size,
                              hipStream_t stream)
{
    const float* x_in = (const float*)d_in[0];
    const int*   ei   = (const int*)d_in[1];
    const float* ea   = (const float*)d_in[2];
    const int N = in_sizes[0] / ND;
    const int E = in_sizes[1] / 2;
    const int* srcs = ei;
    const int* dsts = ei + E;
    const float4* ea4 = (const float4*)ea;

    const float *Wl[3], *bl[3], *Wr[3], *br[3], *We[3], *att[3], *bb[3], *gg[3], *be[3];
    for (int l = 0; l < 3; l++) {
        int b = 3 + 9 * l;
        Wl[l]  = (const float*)d_in[b + 0];
        bl[l]  = (const float*)d_in[b + 1];
        Wr[l]  = (const float*)d_in[b + 2];
        br[l]  = (const float*)d_in[b + 3];
        We[l]  = (const float*)d_in[b + 4];
        att[l] = (const float*)d_in[b + 5];
        bb[l]  = (const float*)d_in[b + 6];
        gg[l]  = (const float*)d_in[b + 7];
        be[l]  = (const float*)d_in[b + 8];
    }
    const float* Wout = (const float*)d_in[30];
    const float* bout = (const float*)d_in[31];

    // padded edge capacity: each of N rows pads to multiple of 4 (+ guard for prefetch)
    const size_t EP = (size_t)E + 3 * (size_t)N + 96;

    char* ws = (char*)d_ws;
    size_t off = 0;
    int* deg        = (int*)(ws + off);      off = alignup(off + (size_t)N * 4);
    int* cursor     = (int*)(ws + off);      off = alignup(off + (size_t)N * 4);
    size_t zero_bytes = off;                 // deg + cursor only
    int* rowstart   = (int*)(ws + off);      off = alignup(off + (size_t)(N + 1) * 4);
    uint4* recs     = (uint4*)(ws + off);    off = alignup(off + EP * 16);
    float4* easum   = (float4*)(ws + off);   off = alignup(off + (size_t)N * 16);
    ushort* xlb     = (ushort*)(ws + off);   off = alignup(off + (size_t)N * ND * 2);
    ushort* xrb     = (ushort*)(ws + off);   off = alignup(off + (size_t)N * ND * 2);
    float* xa       = (float*)(ws + off);    off = alignup(off + (size_t)N * ND * 4);
    ushort* wt      = (ushort*)(ws + off);   off = alignup(off + (size_t)6 * 16384 * 2);
    float* xb       = (float*)d_out;         // layer-1 output lives in d_out

    hipMemsetAsync(d_ws, 0, zero_bytes, stream);

    WSrc wsrc;
    wsrc.p[0] = Wl[0]; wsrc.p[1] = Wr[0];
    wsrc.p[2] = Wl[1]; wsrc.p[3] = Wr[1];
    wsrc.p[4] = Wl[2]; wsrc.p[5] = Wr[2];

    int pthreads = WTHREADS + (E + 3) / 4;
    prep_kernel<<<(pthreads + 255) / 256, 256, 0, stream>>>(wsrc, wt, dsts, deg, E);
    scan_kernel<<<1, 1024, 0, stream>>>(deg, rowstart, N);
    int sthreads = E + N + 96;
    scatter_kernel<<<(sthreads + 255) / 256, 256, 0, stream>>>(srcs, dsts, ea4, rowstart, deg,
                                                               cursor, recs, E, N);

    int gblocks = (N + 63) / 64;
    int ablocks = (N + 3) / 4;

    const ushort* WT0l = wt;
    const ushort* WT0r = wt + 16384;
    const ushort* WT1l = wt + 2 * 16384;
    const ushort* WT1r = wt + 3 * 16384;
    const ushort* WT2l = wt + 4 * 16384;
    const ushort* WT2r = wt + 5 * 16384;

    // layer 0 (computes + stores easum inline)
    gemm_mfma<<<gblocks, 256, 0, stream>>>(x_in, WT0l, bl[0], WT0r, br[0], xlb, xrb, N);
    attn_concat<true><<<ablocks, 256, 0, stream>>>(xlb, xrb, x_in, rowstart, deg, recs, easum,
                                                   We[0], att[0], bb[0], gg[0], be[0], xa, N);
    // layer 1
    gemm_mfma<<<gblocks, 256, 0, stream>>>(xa, WT1l, bl[1], WT1r, br[1], xlb, xrb, N);
    attn_concat<false><<<ablocks, 256, 0, stream>>>(xlb, xrb, xa, rowstart, deg, recs, easum,
                                                    We[1], att[1], bb[1], gg[1], be[1], xb, N);
    // layer 2 + output projection
    gemm_mfma<<<gblocks, 256, 0, stream>>>(xb, WT2l, bl[2], WT2r, br[2], xlb, xrb, N);
    attn_final<<<ablocks, 256, 0, stream>>>(xlb, xrb, rowstart, deg, recs, easum,
                                            We[2], att[2], bb[2], gg[2], be[2],
                                            Wout, bout, (float*)d_out, N);
}

// Round 14
// 418.835 us; speedup vs baseline: 1.0273x; 1.0273x over previous
//
#include <hip/hip_runtime.h>
#include <hip/hip_bf16.h>

#define ND 128   // node feature dim (= H*C)
#define NH 8
#define NC 16

typedef float v2f __attribute__((ext_vector_type(2)));
typedef short bf16x8 __attribute__((ext_vector_type(8)));
typedef float f32x4 __attribute__((ext_vector_type(4)));

static inline size_t alignup(size_t x){ return (x + 255) & ~size_t(255); }

__device__ __forceinline__ ushort f2bf(float f){
    __hip_bfloat16 h = __float2bfloat16(f);
    return *reinterpret_cast<ushort*>(&h);
}

// unpack 2 packed bf16 (lo=ch0, hi=ch1) to packed f32 pair
__device__ __forceinline__ v2f unpack_bf2(uint u){
    v2f r;
    r.x = __uint_as_float(u << 16);
    r.y = __uint_as_float(u & 0xffff0000u);
    return r;
}

__device__ __forceinline__ v2f lrelu2(v2f z){
    v2f s = z * 0.2f;
    v2f r;
    r.x = fmaxf(z.x, s.x);
    r.y = fmaxf(z.y, s.y);
    return r;
}

// sum over each aligned 8-lane group (head group), pure-VALU DPP butterfly
__device__ __forceinline__ float hred8(float x){
    int y;
    y = __builtin_amdgcn_mov_dpp(__float_as_int(x), 0xB1, 0xF, 0xF, true);
    x += __int_as_float(y);
    y = __builtin_amdgcn_mov_dpp(__float_as_int(x), 0x4E, 0xF, 0xF, true);
    x += __int_as_float(y);
    y = __builtin_amdgcn_mov_dpp(__float_as_int(x), 0x141, 0xF, 0xF, true);
    x += __int_as_float(y);
    return x;
}

// ---------------- fused prep: weight transpose/convert + degree histogram ----------------

struct WSrc { const float* p[6]; };

#define WTHREADS (6 * 16384)

__global__ void prep_kernel(WSrc s, ushort* __restrict__ wt,
                            const int* __restrict__ dsts, int* __restrict__ deg, int E)
{
    int id = blockIdx.x * blockDim.x + threadIdx.x;
    if (id < WTHREADS) {
        int m = id >> 14;
        int r = id & 16383;
        int n = r >> 7, k = r & 127;
        wt[(size_t)m * 16384 + n * 128 + k] = f2bf(s.p[m][k * 128 + n]);
    } else {
        int e4 = (id - WTHREADS) * 4;
        if (e4 + 3 < E) {
            int4 d = *(const int4*)(dsts + e4);
            atomicAdd(&deg[d.x], 1);
            atomicAdd(&deg[d.y], 1);
            atomicAdd(&deg[d.z], 1);
            atomicAdd(&deg[d.w], 1);
        } else if (e4 < E) {
            for (int e = e4; e < E; ++e) atomicAdd(&deg[dsts[e]], 1);
        }
    }
}

// rowstart = exclusive cumsum of PADDED degrees (each row padded to multiple of 4), int4-vectorized
__global__ __launch_bounds__(1024) void scan_kernel(const int* __restrict__ deg,
                                                    int* __restrict__ rowstart, int n)
{
    __shared__ int wsum[16];
    int tid = threadIdx.x;
    int lane = tid & 63, wid = tid >> 6;
    int carry = 0;
    for (int base = 0; base < n; base += 4096) {
        int idx = base + tid * 4;
        int4 d = make_int4(0, 0, 0, 0);
        if (idx + 3 < n) d = *(const int4*)(deg + idx);
        else {
            if (idx < n)     d.x = deg[idx];
            if (idx + 1 < n) d.y = deg[idx + 1];
            if (idx + 2 < n) d.z = deg[idx + 2];
        }
        int p0 = (d.x + 3) & ~3, p1 = (d.y + 3) & ~3;
        int p2 = (d.z + 3) & ~3, p3 = (d.w + 3) & ~3;
        int tsum = p0 + p1 + p2 + p3;
        int s = tsum;
        #pragma unroll
        for (int o = 1; o < 64; o <<= 1) {
            int t = __shfl_up(s, o);
            if (lane >= o) s += t;
        }
        if (lane == 63) wsum[wid] = s;
        __syncthreads();
        int off = carry;
        #pragma unroll
        for (int w = 0; w < 16; ++w) {
            int ws_ = wsum[w];
            if (w < wid) off += ws_;
        }
        int total = 0;
        #pragma unroll
        for (int w = 0; w < 16; ++w) total += wsum[w];
        int excl = off + (s - tsum);
        if (idx < n)     rowstart[idx]     = excl;
        if (idx + 1 < n) rowstart[idx + 1] = excl + p0;
        if (idx + 2 < n) rowstart[idx + 2] = excl + p0 + p1;
        if (idx + 3 < n) rowstart[idx + 3] = excl + p0 + p1 + p2;
        carry += total;
        __syncthreads();
    }
    if (tid == 0) rowstart[n] = carry;
}

// fused scatter (ONE random 16B record write per edge) + padfill (pad slots + guard)
// record: {src*256, ea_bf16(ch0,ch1), ea_bf16(ch2,ch3), 0}
__global__ void scatter_kernel(const int* __restrict__ srcs, const int* __restrict__ dsts,
                               const float4* __restrict__ ea4,
                               const int* __restrict__ rowstart, const int* __restrict__ deg,
                               int* __restrict__ cursor, uint4* __restrict__ recs, int E, int n)
{
    int id = blockIdx.x * blockDim.x + threadIdx.x;
    if (id < E) {
        int d = dsts[id];
        int pos = rowstart[d] + atomicAdd(&cursor[d], 1);
        float4 a = ea4[id];
        recs[pos] = make_uint4((uint)(srcs[id] << 8),
                               (uint)f2bf(a.x) | ((uint)f2bf(a.y) << 16),
                               (uint)f2bf(a.z) | ((uint)f2bf(a.w) << 16), 0u);
    } else if (id < E + n) {
        int v = id - E;
        int d = deg[v];
        int p = rowstart[v] + d;
        int pe = rowstart[v] + ((d + 3) & ~3);
        for (; p < pe; ++p) recs[p] = make_uint4(0u, 0u, 0u, 0u);
    } else if (id < E + n + 96) {
        int p = rowstart[n] + (id - E - n);
        recs[p] = make_uint4(0u, 0u, 0u, 0u);
    }
}

// per-dst MEAN of incoming edge attrs (self-loop fill), computed once, reused by 3 layers
__global__ void easum_kernel(const int* __restrict__ rowstart, const int* __restrict__ deg,
                             const uint4* __restrict__ recs, float4* __restrict__ easum, int n)
{
    int v = blockIdx.x * blockDim.x + threadIdx.x;
    if (v >= n) return;
    int p0 = rowstart[v], d = deg[v];
    float sx = 0.f, sy = 0.f, sz = 0.f, sw = 0.f;
    for (int p = p0; p < p0 + d; ++p) {
        uint4 a = recs[p];
        sx += __uint_as_float(a.y << 16);
        sy += __uint_as_float(a.y & 0xffff0000u);
        sz += __uint_as_float(a.z << 16);
        sw += __uint_as_float(a.z & 0xffff0000u);
    }
    float inv = 1.0f / (float)(d > 0 ? d : 1);
    easum[v] = make_float4(sx * inv, sy * inv, sz * inv, sw * inv);
}

// ---------------- MFMA GEMM: XL,XR (bf16) = X@{Wl,Wr}+{bl,br} ----------------
// A = X tile split hi/lo bf16 (error ~2^-17), B = WT bf16. 16x16x32 MFMA. (r9-validated)

__global__ __launch_bounds__(256) void gemm_mfma(
    const float* __restrict__ X,
    const ushort* __restrict__ WTl, const float* __restrict__ bl,
    const ushort* __restrict__ WTr, const float* __restrict__ br,
    ushort* __restrict__ XLB, ushort* __restrict__ XRB, int nrows)
{
    __shared__ ushort xhi[64][136];
    __shared__ ushort xlo[64][136];
    int tid = threadIdx.x;
    int row0 = blockIdx.x * 64;

    const float4* X4 = (const float4*)X;
    #pragma unroll
    for (int i = tid; i < 64*32; i += 256) {
        int r = i >> 5, c = i & 31;
        float4 v = make_float4(0.f, 0.f, 0.f, 0.f);
        if (row0 + r < nrows) v = X4[(size_t)(row0 + r) * 32 + c];
        ushort4 h, l;
        h.x = f2bf(v.x); l.x = f2bf(v.x - __uint_as_float((uint)h.x << 16));
        h.y = f2bf(v.y); l.y = f2bf(v.y - __uint_as_float((uint)h.y << 16));
        h.z = f2bf(v.z); l.z = f2bf(v.z - __uint_as_float((uint)h.z << 16));
        h.w = f2bf(v.w); l.w = f2bf(v.w - __uint_as_float((uint)h.w << 16));
        *(ushort4*)&xhi[r][c * 4] = h;
        *(ushort4*)&xlo[r][c * 4] = l;
    }
    __syncthreads();

    int lane = tid & 63;
    int wid = tid >> 6;
    int c15 = lane & 15;
    int kblk = lane >> 4;
    int rowb = wid * 16;

    f32x4 accl[8], accr[8];
    #pragma unroll
    for (int nt = 0; nt < 8; ++nt) {
        float bvl = bl[nt * 16 + c15];
        float bvr = br[nt * 16 + c15];
        accl[nt] = (f32x4){bvl, bvl, bvl, bvl};
        accr[nt] = (f32x4){bvr, bvr, bvr, bvr};
    }

    const bf16x8* WL8 = (const bf16x8*)WTl;
    const bf16x8* WR8 = (const bf16x8*)WTr;

    #pragma unroll
    for (int kc = 0; kc < 4; ++kc) {
        int k0 = kc * 32 + kblk * 8;
        bf16x8 ahi = *(const bf16x8*)&xhi[rowb + c15][k0];
        bf16x8 alo = *(const bf16x8*)&xlo[rowb + c15][k0];
        int kidx = k0 >> 3;
        #pragma unroll
        for (int nt = 0; nt < 8; ++nt) {
            int bi = (nt * 16 + c15) * 16 + kidx;
            bf16x8 bfl = WL8[bi];
            bf16x8 bfr = WR8[bi];
            accl[nt] = __builtin_amdgcn_mfma_f32_16x16x32_bf16(ahi, bfl, accl[nt], 0, 0, 0);
            accl[nt] = __builtin_amdgcn_mfma_f32_16x16x32_bf16(alo, bfl, accl[nt], 0, 0, 0);
            accr[nt] = __builtin_amdgcn_mfma_f32_16x16x32_bf16(ahi, bfr, accr[nt], 0, 0, 0);
            accr[nt] = __builtin_amdgcn_mfma_f32_16x16x32_bf16(alo, bfr, accr[nt], 0, 0, 0);
        }
    }

    int crow = rowb + (lane >> 4) * 4;
    #pragma unroll
    for (int j = 0; j < 4; ++j) {
        int row = row0 + crow + j;
        if (row < nrows) {
            #pragma unroll
            for (int nt = 0; nt < 8; ++nt) {
                XLB[(size_t)row * 128 + nt * 16 + c15] = f2bf(accl[nt][j]);
                XRB[(size_t)row * 128 + nt * 16 + c15] = f2bf(accr[nt][j]);
            }
        }
    }
}

// ---------------- GATv2 edge accumulation: 1 wave/dst, 2 ch/lane (packed f32) -----------
// r12 champion structure: unified 16B records (scalar stream, 3 batches in flight),
// gathers 2 batches ahead, guard-zero-filled rows. easum precomputed.
// No max tracking (validated r4-r13).

__device__ __forceinline__ void gat_wave(
    int dstv, int t,
    const uint* __restrict__ xl_u, const uint* __restrict__ xr_u,
    const int* __restrict__ rowstart, const int* __restrict__ deg,
    const uint4* __restrict__ recs, const float4* __restrict__ easum,
    const float* __restrict__ We, const float* __restrict__ att,
    v2f& r_out, float& l_out)
{
    v2f we0  = ((const v2f*)(We))[t];
    v2f we1  = ((const v2f*)(We + ND))[t];
    v2f we2  = ((const v2f*)(We + 2*ND))[t];
    v2f we3  = ((const v2f*)(We + 3*ND))[t];
    v2f attv = ((const v2f*)att)[t] * 1.44269504f;   // log2(e) folded in
    v2f xrv  = unpack_bf2(xr_u[(((uint)dstv) << 6) + t]);

    int p0 = __builtin_amdgcn_readfirstlane(rowstart[dstv]);
    int dv = __builtin_amdgcn_readfirstlane(deg[dstv]);
    int nb = (dv + 3) >> 2;

    uint xsw = xl_u[(((uint)dstv) << 6) + t];   // self-loop xl

    const uint4* rp = recs + p0;                // wave-uniform -> scalar loads
    const char* xlc = (const char*)xl_u;
    uint t4 = (uint)t * 4u;

    v2f a = {0.f, 0.f};
    float lsum = 0.f;

    // prologue: records for batches 0,1,2; gathers for batches 0,1 (guard zero-filled)
    uint4 rA0 = rp[0],  rA1 = rp[1],  rA2 = rp[2],  rA3 = rp[3];
    uint4 rB0 = rp[4],  rB1 = rp[5],  rB2 = rp[6],  rB3 = rp[7];
    uint4 rC0 = rp[8],  rC1 = rp[9],  rC2 = rp[10], rC3 = rp[11];
    uint xA0 = *(const uint*)(xlc + (rA0.x + t4));
    uint xA1 = *(const uint*)(xlc + (rA1.x + t4));
    uint xA2 = *(const uint*)(xlc + (rA2.x + t4));
    uint xA3 = *(const uint*)(xlc + (rA3.x + t4));
    uint xB0 = *(const uint*)(xlc + (rB0.x + t4));
    uint xB1 = *(const uint*)(xlc + (rB1.x + t4));
    uint xB2 = *(const uint*)(xlc + (rB2.x + t4));
    uint xB3 = *(const uint*)(xlc + (rB3.x + t4));

    for (int ib = 0; ib < nb; ++ib) {
        // gathers for batch ib+2, records for batch ib+3
        uint xC0 = *(const uint*)(xlc + (rC0.x + t4));
        uint xC1 = *(const uint*)(xlc + (rC1.x + t4));
        uint xC2 = *(const uint*)(xlc + (rC2.x + t4));
        uint xC3 = *(const uint*)(xlc + (rC3.x + t4));
        uint4 rD0 = rp[ib*4 + 12], rD1 = rp[ib*4 + 13];
        uint4 rD2 = rp[ib*4 + 14], rD3 = rp[ib*4 + 15];

        // unpack ea from current batch's records (wave-uniform)
        float e0x = __uint_as_float(rA0.y << 16), e0y = __uint_as_float(rA0.y & 0xffff0000u);
        float e0z = __uint_as_float(rA0.z << 16), e0w = __uint_as_float(rA0.z & 0xffff0000u);
        float e1x = __uint_as_float(rA1.y << 16), e1y = __uint_as_float(rA1.y & 0xffff0000u);
        float e1z = __uint_as_float(rA1.z << 16), e1w = __uint_as_float(rA1.z & 0xffff0000u);
        float e2x = __uint_as_float(rA2.y << 16), e2y = __uint_as_float(rA2.y & 0xffff0000u);
        float e2z = __uint_as_float(rA2.z << 16), e2w = __uint_as_float(rA2.z & 0xffff0000u);
        float e3x = __uint_as_float(rA3.y << 16), e3y = __uint_as_float(rA3.y & 0xffff0000u);
        float e3z = __uint_as_float(rA3.z << 16), e3w = __uint_as_float(rA3.z & 0xffff0000u);

        // b = xr + ea @ We  (packed f32)
        v2f b0 = xrv + we0*e0x + we1*e0y + we2*e0z + we3*e0w;
        v2f b1 = xrv + we0*e1x + we1*e1y + we2*e1z + we3*e1w;
        v2f b2 = xrv + we0*e2x + we1*e2y + we2*e2z + we3*e2w;
        v2f b3 = xrv + we0*e3x + we1*e3y + we2*e3z + we3*e3w;

        v2f x0 = unpack_bf2(xA0);
        v2f x1 = unpack_bf2(xA1);
        v2f x2 = unpack_bf2(xA2);
        v2f x3 = unpack_bf2(xA3);

        v2f l0 = lrelu2(x0 + b0);
        v2f l1 = lrelu2(x1 + b1);
        v2f l2 = lrelu2(x2 + b2);
        v2f l3 = lrelu2(x3 + b3);

        v2f q0 = l0 * attv;
        v2f q1 = l1 * attv;
        v2f q2 = l2 * attv;
        v2f q3 = l3 * attv;
        float pt0 = q0.x + q0.y;
        float pt1 = q1.x + q1.y;
        float pt2 = q2.x + q2.y;
        float pt3 = q3.x + q3.y;

        // mask only in the last batch (wave-uniform branch)
        if (ib == nb - 1) {
            int live = dv - ib*4;
            pt1 = (live > 1) ? pt1 : -1e30f;
            pt2 = (live > 2) ? pt2 : -1e30f;
            pt3 = (live > 3) ? pt3 : -1e30f;
        }

        // per-head logit reduce (DPP, 4 independent chains)
        float al0 = hred8(pt0);
        float al1 = hred8(pt1);
        float al2 = hred8(pt2);
        float al3 = hred8(pt3);

        // no-max softmax accumulation in log2 domain
        float pe0 = exp2f(al0);
        float pe1 = exp2f(al1);
        float pe2 = exp2f(al2);
        float pe3 = exp2f(al3);
        lsum += (pe0 + pe1) + (pe2 + pe3);
        a += x0 * pe0;
        a += x1 * pe1;
        a += x2 * pe2;
        a += x3 * pe3;

        xA0 = xB0; xA1 = xB1; xA2 = xB2; xA3 = xB3;
        xB0 = xC0; xB1 = xC1; xB2 = xC2; xB3 = xC3;
        rA0 = rB0; rA1 = rB1; rA2 = rB2; rA3 = rB3;
        rB0 = rC0; rB1 = rC1; rB2 = rC2; rB3 = rC3;
        rC0 = rD0; rC1 = rD1; rC2 = rD2; rC3 = rD3;
    }

    // self loop: ea = precomputed mean of incoming, src = dst
    float4 em = easum[dstv];                    // uniform -> scalar load
    v2f xs = unpack_bf2(xsw);
    v2f bs = xrv + we0*em.x + we1*em.y + we2*em.z + we3*em.w;
    v2f ls = lrelu2(xs + bs);
    v2f qs = ls * attv;
    float al = hred8(qs.x + qs.y);
    float pe = exp2f(al);
    l_out = lsum + pe;
    r_out = a + xs * pe;
}

// layers 0,1: concat heads, +bias, ELU, LN(128), residual. 4 dst per 256-thread block.
__global__ __launch_bounds__(256) void attn_concat(
    const ushort* __restrict__ xlb, const ushort* __restrict__ xrb,
    const float* __restrict__ xin,
    const int* __restrict__ rowstart, const int* __restrict__ deg,
    const uint4* __restrict__ recs, const float4* __restrict__ easum,
    const float* __restrict__ We, const float* __restrict__ att,
    const float* __restrict__ bias, const float* __restrict__ g, const float* __restrict__ be,
    float* __restrict__ out, int n)
{
    int wid = threadIdx.x >> 6;
    int t = threadIdx.x & 63;
    int dstv = blockIdx.x * 4 + wid;
    if (dstv >= n) return;

    v2f av; float l;
    gat_wave(dstv, t, (const uint*)xlb, (const uint*)xrb, rowstart, deg, recs, easum,
             We, att, av, l);

    v2f bv = ((const v2f*)bias)[t];
    float linv = 1.0f / l;
    v2f h = av * linv + bv;
    h.x = h.x > 0.f ? h.x : (__expf(h.x) - 1.0f);   // ELU
    h.y = h.y > 0.f ? h.y : (__expf(h.y) - 1.0f);

    float ss = h.x + h.y, qq = h.x*h.x + h.y*h.y;
    #pragma unroll
    for (int o = 1; o < 64; o <<= 1) { ss += __shfl_xor(ss, o); qq += __shfl_xor(qq, o); }
    float mu = ss * (1.0f / ND);
    float var = qq * (1.0f / ND) - mu * mu;
    float rstd = rsqrtf(var + 1e-5f);

    v2f gv  = ((const v2f*)g)[t];
    v2f bev = ((const v2f*)be)[t];
    v2f xiv = ((const v2f*)(xin + (size_t)dstv * ND))[t];
    v2f o2 = (h - mu) * rstd * gv + bev + xiv;
    ((v2f*)(out + (size_t)dstv * ND))[t] = o2;
}

// layer 2: mean over heads, +bias, ELU, LN(16), @Wout[16,128]+bout
__global__ __launch_bounds__(256) void attn_final(
    const ushort* __restrict__ xlb, const ushort* __restrict__ xrb,
    const int* __restrict__ rowstart, const int* __restrict__ deg,
    const uint4* __restrict__ recs, const float4* __restrict__ easum,
    const float* __restrict__ We, const float* __restrict__ att,
    const float* __restrict__ b2, const float* __restrict__ g2, const float* __restrict__ be2,
    const float* __restrict__ Wout, const float* __restrict__ bout,
    float* __restrict__ out, int n)
{
    __shared__ float h16s[4][16];
    int wid = threadIdx.x >> 6;
    int t = threadIdx.x & 63;
    int dstv = blockIdx.x * 4 + wid;
    if (dstv >= n) return;

    v2f av; float l;
    gat_wave(dstv, t, (const uint*)xlb, (const uint*)xrb, rowstart, deg, recs, easum,
             We, att, av, l);
    float linv = 1.0f / l;
    float v0 = av.x * linv, v1 = av.y * linv;

    // mean over 8 heads: sum over lanes differing in bits 3,4,5
    #pragma unroll
    for (int o = 8; o < 64; o <<= 1) { v0 += __shfl_xor(v0, o); v1 += __shfl_xor(v1, o); }
    int cc = t & 7;   // channel pair index: channels 2cc, 2cc+1
    float2 b2v = ((const float2*)b2)[cc];
    v0 = v0 * (1.0f / NH) + b2v.x;
    v1 = v1 * (1.0f / NH) + b2v.y;
    v0 = v0 > 0.f ? v0 : (__expf(v0) - 1.0f);
    v1 = v1 > 0.f ? v1 : (__expf(v1) - 1.0f);

    // LN over 16 (values duplicated across the 8 head-groups)
    float ss = v0 + v1, qq = v0*v0 + v1*v1;
    #pragma unroll
    for (int o = 1; o < 8; o <<= 1) { ss += __shfl_xor(ss, o); qq += __shfl_xor(qq, o); }
    float mu = ss * (1.0f / NC);
    float var = qq * (1.0f / NC) - mu * mu;
    float rstd = rsqrtf(var + 1e-5f);
    float2 g2v = ((const float2*)g2)[cc];
    float2 be2v = ((const float2*)be2)[cc];
    float t0 = (v0 - mu) * rstd * g2v.x + be2v.x;
    float t1 = (v1 - mu) * rstd * g2v.y + be2v.y;

    if (t < 8) { h16s[wid][2*t] = t0; h16s[wid][2*t + 1] = t1; }

    float2 ov = ((const float2*)bout)[t];
    #pragma unroll
    for (int k = 0; k < NC; k++) {
        float hk = h16s[wid][k];
        float2 wv = ((const float2*)Wout)[k * 64 + t];
        ov.x = fmaf(hk, wv.x, ov.x);
        ov.y = fmaf(hk, wv.y, ov.y);
    }
    ((float2*)(out + (size_t)dstv * ND))[t] = ov;
}

// ---------------- launch ----------------

extern "C" void kernel_launch(void* const* d_in, const int* in_sizes, int n_in,
                              void* d_out, int out_size, void* d_ws, size_t ws_size,
                              hipStream_t stream)
{
    const float* x_in = (const float*)d_in[0];
    const int*   ei   = (const int*)d_in[1];
    const float* ea   = (const float*)d_in[2];
    const int N = in_sizes[0] / ND;
    const int E = in_sizes[1] / 2;
    const int* srcs = ei;
    const int* dsts = ei + E;
    const float4* ea4 = (const float4*)ea;

    const float *Wl[3], *bl[3], *Wr[3], *br[3], *We[3], *att[3], *bb[3], *gg[3], *be[3];
    for (int l = 0; l < 3; l++) {
        int b = 3 + 9 * l;
        Wl[l]  = (const float*)d_in[b + 0];
        bl[l]  = (const float*)d_in[b + 1];
        Wr[l]  = (const float*)d_in[b + 2];
        br[l]  = (const float*)d_in[b + 3];
        We[l]  = (const float*)d_in[b + 4];
        att[l] = (const float*)d_in[b + 5];
        bb[l]  = (const float*)d_in[b + 6];
        gg[l]  = (const float*)d_in[b + 7];
        be[l]  = (const float*)d_in[b + 8];
    }
    const float* Wout = (const float*)d_in[30];
    const float* bout = (const float*)d_in[31];

    // padded edge capacity: each of N rows pads to multiple of 4 (+ guard for prefetch)
    const size_t EP = (size_t)E + 3 * (size_t)N + 96;

    char* ws = (char*)d_ws;
    size_t off = 0;
    int* deg        = (int*)(ws + off);      off = alignup(off + (size_t)N * 4);
    int* cursor     = (int*)(ws + off);      off = alignup(off + (size_t)N * 4);
    size_t zero_bytes = off;                 // deg + cursor only
    int* rowstart   = (int*)(ws + off);      off = alignup(off + (size_t)(N + 1) * 4);
    uint4* recs     = (uint4*)(ws + off);    off = alignup(off + EP * 16);
    float4* easum   = (float4*)(ws + off);   off = alignup(off + (size_t)N * 16);
    ushort* xlb     = (ushort*)(ws + off);   off = alignup(off + (size_t)N * ND * 2);
    ushort* xrb     = (ushort*)(ws + off);   off = alignup(off + (size_t)N * ND * 2);
    float* xa       = (float*)(ws + off);    off = alignup(off + (size_t)N * ND * 4);
    ushort* wt      = (ushort*)(ws + off);   off = alignup(off + (size_t)6 * 16384 * 2);
    float* xb       = (float*)d_out;         // layer-1 output lives in d_out

    hipMemsetAsync(d_ws, 0, zero_bytes, stream);

    WSrc wsrc;
    wsrc.p[0] = Wl[0]; wsrc.p[1] = Wr[0];
    wsrc.p[2] = Wl[1]; wsrc.p[3] = Wr[1];
    wsrc.p[4] = Wl[2]; wsrc.p[5] = Wr[2];

    int pthreads = WTHREADS + (E + 3) / 4;
    prep_kernel<<<(pthreads + 255) / 256, 256, 0, stream>>>(wsrc, wt, dsts, deg, E);
    scan_kernel<<<1, 1024, 0, stream>>>(deg, rowstart, N);
    int sthreads = E + N + 96;
    scatter_kernel<<<(sthreads + 255) / 256, 256, 0, stream>>>(srcs, dsts, ea4, rowstart, deg,
                                                               cursor, recs, E, N);
    easum_kernel<<<(N + 255) / 256, 256, 0, stream>>>(rowstart, deg, recs, easum, N);

    int gblocks = (N + 63) / 64;
    int ablocks = (N + 3) / 4;

    const ushort* WT0l = wt;
    const ushort* WT0r = wt + 16384;
    const ushort* WT1l = wt + 2 * 16384;
    const ushort* WT1r = wt + 3 * 16384;
    const ushort* WT2l = wt + 4 * 16384;
    const ushort* WT2r = wt + 5 * 16384;

    // layer 0
    gemm_mfma<<<gblocks, 256, 0, stream>>>(x_in, WT0l, bl[0], WT0r, br[0], xlb, xrb, N);
    attn_concat<<<ablocks, 256, 0, stream>>>(xlb, xrb, x_in, rowstart, deg, recs, easum,
                                             We[0], att[0], bb[0], gg[0], be[0], xa, N);
    // layer 1
    gemm_mfma<<<gblocks, 256, 0, stream>>>(xa, WT1l, bl[1], WT1r, br[1], xlb, xrb, N);
    attn_concat<<<ablocks, 256, 0, stream>>>(xlb, xrb, xa, rowstart, deg, recs, easum,
                                             We[1], att[1], bb[1], gg[1], be[1], xb, N);
    // layer 2 + output projection
    gemm_mfma<<<gblocks, 256, 0, stream>>>(xb, WT2l, bl[2], WT2r, br[2], xlb, xrb, N);
    attn_final<<<ablocks, 256, 0, stream>>>(xlb, xrb, rowstart, deg, recs, easum,
                                            We[2], att[2], bb[2], gg[2], be[2],
                                            Wout, bout, (float*)d_out, N);
}